// Round 8
// baseline (183.581 us; speedup 1.0000x reference)
//
#include <hip/hip_runtime.h>

// Problem constants (fixed by reference)
#define B_ 16
#define C_ 64
#define T_ 2048
#define O_ 64
#define KNN 3

typedef short short8   __attribute__((ext_vector_type(8)));   // 8 bf16
typedef float f32x4    __attribute__((ext_vector_type(4)));
typedef unsigned short ushortx4 __attribute__((ext_vector_type(4)));

// Workspace layout (float slots). Total ~16.8 MB (<< 256 MiB ws).
#define XT_OFF 0                              // fp32 xT[b][t][c]          : B*T*64
#define XS_OFF (XT_OFF + B_ * T_ * C_)        // ushort xs[b][t][128] hi|lo
#define NSQ_OFF (XS_OFF + B_ * T_ * C_)       // fp32 nsq[b*T+t]
#define WT_OFF (NSQ_OFF + B_ * T_)            // fp32 Wt[m][o], m=k*64+c   : 192*64

__device__ inline ushort bf16_rne(float f) {
    union { float f; unsigned u; } cv; cv.f = f;
    unsigned u = cv.u;
    u += 0x7FFF + ((u >> 16) & 1);
    return (ushort)(u >> 16);
}
__device__ inline float bf16_val(ushort h) {
    union { unsigned u; float f; } cv; cv.u = ((unsigned)h) << 16; return cv.f;
}

// ---------------------------------------------------------------------------
// Prep (validated R4-R7): x (B,C,T) -> xT (B,T,C) fp32, xs bf16 [hi|lo], nsq,
//       W (O,C,K) -> Wt[k*64+c][o]
// ---------------------------------------------------------------------------
__global__ __launch_bounds__(256) void prep_kernel(const float* __restrict__ x,
                                                   const float* __restrict__ W,
                                                   float* __restrict__ ws) {
    float*  xT  = ws + XT_OFF;
    ushort* xs  = (ushort*)(ws + XS_OFF);
    float*  nsq = ws + NSQ_OFF;
    float*  Wt  = ws + WT_OFF;
    int blk = blockIdx.x;
    int tid = threadIdx.x;
    if (blk < B_ * (T_ / 64)) {
        int b  = blk / (T_ / 64);
        int t0 = (blk % (T_ / 64)) * 64;
        __shared__ float tl[64 * 65];
        #pragma unroll
        for (int r = 0; r < 16; ++r) {
            int e = r * 256 + tid;
            int c = e >> 6, t = e & 63;
            tl[c * 65 + t] = x[(b * C_ + c) * T_ + t0 + t];
        }
        __syncthreads();
        #pragma unroll
        for (int r = 0; r < 16; ++r) {
            int e = r * 256 + tid;
            int t = e >> 6, c = e & 63;
            float v = tl[c * 65 + t];
            size_t rowg = (size_t)(b * T_ + t0 + t);
            xT[rowg * 64 + c] = v;
            ushort hi = bf16_rne(v);
            float  fr = v - bf16_val(hi);
            ushort lo = bf16_rne(fr);
            xs[rowg * 128 + c]      = hi;
            xs[rowg * 128 + 64 + c] = lo;
        }
        if (tid < 64) {
            float s = 0.f;
            #pragma unroll
            for (int c = 0; c < 64; ++c) { float v = tl[c * 65 + tid]; s = fmaf(v, v, s); }
            nsq[b * T_ + t0 + tid] = s;
        }
    } else {
        int e = (blk - B_ * (T_ / 64)) * 256 + tid;
        if (e < O_ * C_ * KNN) {
            int o = e / (C_ * KNN);
            int c = (e / KNN) % C_;
            int k = e % KNN;
            Wt[(k * 64 + c) * O_ + o] = W[e];
        }
    }
}

// ---------------------------------------------------------------------------
// MEGA: screen (MFMA) + merge + exact refine + conv, one launch.
// Block = (b, 128-i tile), 256 blocks (~1/CU), b = bid&15 -> XCD b%8 so each
// batch's xs/xT stay L2-local. Phase K: 64 double-buffered global_load_lds
// rounds over all 2048 j (R7-validated swizzle/MFMA structure; 11-bit ids).
// Epilogue: per-row top-8 of 16 stripe-keys (fmin+7*med3), decode -> LDS.
// Phase R: quarter-wave butterfly exact fp32 re-rank (validated R6/R7).
// Phase C: conv in 4x 32-row sub-tiles (bitwise-identical fmaf chain to R7).
// ---------------------------------------------------------------------------
__global__ __launch_bounds__(256) void mega_kernel(const float* __restrict__ ws_c,
                                                   const float* __restrict__ bias,
                                                   float* __restrict__ out) {
    const float*  xT  = ws_c + XT_OFF;
    const ushort* xs  = (const ushort*)(ws_c + XS_OFF);
    const float*  nsq = ws_c + NSQ_OFF;
    const float*  Wt  = ws_c + WT_OFF;

    __shared__ __align__(16) ushort jbuf[2][32 * 128];   // 16 KB, XOR-swizzled
    __shared__ float  nsqs[T_];                          // 8 KB
    __shared__ ushort jcand[128 * 8];                    // 2 KB
    __shared__ int    jsel3[128 * 3];                    // 1.5 KB
    __shared__ float  g_s[192 * 32];                     // 24 KB

    int bid = blockIdx.x;
    int b   = bid & 15;                 // XCD = b%8: batch-local L2
    int m   = bid >> 4;                 // i-tile 0..15 (128 rows each)
    int i0  = m * 128;
    int tid = threadIdx.x;
    int w   = tid >> 6, l = tid & 63, lr = l & 15, lq = l >> 4;
    const ushort* xsb = xs + (size_t)b * T_ * 128;
    int bT = b * T_;

    ((float4*)nsqs)[tid]       = ((const float4*)(nsq + bT))[tid];
    ((float4*)nsqs)[tid + 256] = ((const float4*)(nsq + bT))[tid + 256];

    // B-operand frags for 2 i-sets: rows i0+w*32+lr (A) and +16 (B)
    short8 bA0, bA1, bA4, bA5, bB0, bB1, bB4, bB5;
    {
        const ushort* ia = xsb + (size_t)(i0 + w * 32 + lr) * 128 + lq * 8;
        bA0 = *(const short8*)(ia + 0);  bA1 = *(const short8*)(ia + 32);
        bA4 = *(const short8*)(ia + 64); bA5 = *(const short8*)(ia + 96);
        const ushort* ib2 = ia + 16 * 128;
        bB0 = *(const short8*)(ib2 + 0);  bB1 = *(const short8*)(ib2 + 32);
        bB4 = *(const short8*)(ib2 + 64); bB5 = *(const short8*)(ib2 + 96);
    }
    float niA = nsq[bT + i0 + w * 32 + lr] + 4.0f;
    float niB = nsq[bT + i0 + w * 32 + 16 + lr] + 4.0f;

    const float INF = __builtin_inff();
    float kA0 = INF, kA1 = INF, kA2 = INF, kA3 = INF;
    float kB0 = INF, kB1 = INF, kB2 = INF, kB3 = INF;

    int cSw = lr ^ (w * 4 + lq);                 // swizzled source chunk
    #define ISSUE_DMA(jsv, bufv) {                                               \
        _Pragma("unroll")                                                        \
        for (int p = 0; p < 2; ++p) {                                            \
            int rloc = p * 16 + w * 4 + lq;                                      \
            const ushort* gp = xsb + (size_t)((jsv) * 32 + rloc) * 128 + cSw * 8; \
            __builtin_amdgcn_global_load_lds(                                    \
                (const __attribute__((address_space(1))) void*)gp,               \
                (__attribute__((address_space(3))) void*)(jbuf[bufv] + (p * 16 + w * 4) * 128), \
                16, 0, 0);                                                       \
        } }

    ISSUE_DMA(0, 0);

    #pragma unroll 1
    for (int js = 0; js < 64; ++js) {
        asm volatile("s_waitcnt vmcnt(0)" ::: "memory");  // my round-js DMA done
        __syncthreads();                                  // all DMA visible; other buf free
        if (js < 63) ISSUE_DMA(js + 1, (js + 1) & 1);     // overlaps compute below
        const char* jb8 = (const char*)jbuf[js & 1];
        #pragma unroll
        for (int tile = 0; tile < 2; ++tile) {
            const char* rowp = jb8 + (tile * 16 + lr) * 256;
            short8 ah0 = *(const short8*)(rowp + ((( 0 + lq) ^ lr) << 4));
            short8 ah1 = *(const short8*)(rowp + ((( 4 + lq) ^ lr) << 4));
            short8 al0 = *(const short8*)(rowp + ((( 8 + lq) ^ lr) << 4));
            short8 al1 = *(const short8*)(rowp + (((12 + lq) ^ lr) << 4));
            f32x4 accA = {0.f, 0.f, 0.f, 0.f};
            f32x4 accB = {0.f, 0.f, 0.f, 0.f};
            accA = __builtin_amdgcn_mfma_f32_16x16x32_bf16(ah0, bA0, accA, 0, 0, 0);
            accB = __builtin_amdgcn_mfma_f32_16x16x32_bf16(ah0, bB0, accB, 0, 0, 0);
            accA = __builtin_amdgcn_mfma_f32_16x16x32_bf16(ah1, bA1, accA, 0, 0, 0);
            accB = __builtin_amdgcn_mfma_f32_16x16x32_bf16(ah1, bB1, accB, 0, 0, 0);
            accA = __builtin_amdgcn_mfma_f32_16x16x32_bf16(al0, bA0, accA, 0, 0, 0);
            accB = __builtin_amdgcn_mfma_f32_16x16x32_bf16(al0, bB0, accB, 0, 0, 0);
            accA = __builtin_amdgcn_mfma_f32_16x16x32_bf16(al1, bA1, accA, 0, 0, 0);
            accB = __builtin_amdgcn_mfma_f32_16x16x32_bf16(al1, bB1, accB, 0, 0, 0);
            accA = __builtin_amdgcn_mfma_f32_16x16x32_bf16(ah0, bA4, accA, 0, 0, 0);
            accB = __builtin_amdgcn_mfma_f32_16x16x32_bf16(ah0, bB4, accB, 0, 0, 0);
            accA = __builtin_amdgcn_mfma_f32_16x16x32_bf16(ah1, bA5, accA, 0, 0, 0);
            accB = __builtin_amdgcn_mfma_f32_16x16x32_bf16(ah1, bB5, accB, 0, 0, 0);
            float4 nv = *(const float4*)(nsqs + js * 32 + tile * 16 + lq * 4);
            int idb = ((js * 2 + tile) << 2) | (lq << 9);   // 11-bit id base
            #define INS(K0, K1, K2, K3, sv, idv) {                                  \
                unsigned uu = (__float_as_uint(sv) & 0xFFFFF800u) | (unsigned)(idv); \
                float kf = __uint_as_float(uu);                                      \
                float n0 = fminf(K0, kf);                                            \
                float n1 = __builtin_amdgcn_fmed3f(K0, K1, kf);                      \
                float n2 = __builtin_amdgcn_fmed3f(K1, K2, kf);                      \
                float n3 = __builtin_amdgcn_fmed3f(K2, K3, kf);                      \
                K0 = n0; K1 = n1; K2 = n2; K3 = n3; }
            {
                float s0 = fmaf(-2.f, accA[0], nv.x + niA); INS(kA0, kA1, kA2, kA3, s0, idb + 0);
                float s1 = fmaf(-2.f, accA[1], nv.y + niA); INS(kA0, kA1, kA2, kA3, s1, idb + 1);
                float s2 = fmaf(-2.f, accA[2], nv.z + niA); INS(kA0, kA1, kA2, kA3, s2, idb + 2);
                float s3 = fmaf(-2.f, accA[3], nv.w + niA); INS(kA0, kA1, kA2, kA3, s3, idb + 3);
            }
            {
                float s0 = fmaf(-2.f, accB[0], nv.x + niB); INS(kB0, kB1, kB2, kB3, s0, idb + 0);
                float s1 = fmaf(-2.f, accB[1], nv.y + niB); INS(kB0, kB1, kB2, kB3, s1, idb + 1);
                float s2 = fmaf(-2.f, accB[2], nv.z + niB); INS(kB0, kB1, kB2, kB3, s2, idb + 2);
                float s3 = fmaf(-2.f, accB[3], nv.w + niB); INS(kB0, kB1, kB2, kB3, s3, idb + 3);
            }
            #undef INS
        }
    }

    // Epilogue: per-row top-8 of 16 stripe-keys, decode -> jcand in LDS.
    __syncthreads();
    float* fbuf = (float*)jbuf;                 // 128 rows x 16 keys = 8 KB
    {
        float* pa = fbuf + (w * 32 + lr) * 16 + lq * 4;
        pa[0] = kA0; pa[1] = kA1; pa[2] = kA2; pa[3] = kA3;
        float* pb = fbuf + (w * 32 + 16 + lr) * 16 + lq * 4;
        pb[0] = kB0; pb[1] = kB1; pb[2] = kB2; pb[3] = kB3;
    }
    __syncthreads();
    if (l < 32) {
        int rloc = w * 32 + l;
        const float* pr = fbuf + rloc * 16;
        float m0 = INF, m1 = INF, m2 = INF, m3 = INF;
        float m4 = INF, m5 = INF, m6 = INF, m7 = INF;
        #pragma unroll
        for (int q2 = 0; q2 < 16; ++q2) {
            float kf = pr[q2];
            float n0 = fminf(m0, kf);
            float n1 = __builtin_amdgcn_fmed3f(m0, m1, kf);
            float n2 = __builtin_amdgcn_fmed3f(m1, m2, kf);
            float n3 = __builtin_amdgcn_fmed3f(m2, m3, kf);
            float n4 = __builtin_amdgcn_fmed3f(m3, m4, kf);
            float n5 = __builtin_amdgcn_fmed3f(m4, m5, kf);
            float n6 = __builtin_amdgcn_fmed3f(m5, m6, kf);
            float n7 = __builtin_amdgcn_fmed3f(m6, m7, kf);
            m0 = n0; m1 = n1; m2 = n2; m3 = n3;
            m4 = n4; m5 = n5; m6 = n6; m7 = n7;
        }
        ushort* dst = jcand + rloc * 8;
        #define DEC(mf, slot) { unsigned u = __float_as_uint(mf) & 2047u;            \
            dst[slot] = (ushort)((((u >> 2) & 127u) << 4) + ((u >> 9) << 2) + (u & 3)); }
        DEC(m0, 0); DEC(m1, 1); DEC(m2, 2); DEC(m3, 3);
        DEC(m4, 4); DEC(m5, 5); DEC(m6, 6); DEC(m7, 7);
        #undef DEC
    }
    __syncthreads();

    // --- Phase R: exact fp32 refine, quarter-wave per row, 8 passes.
    int qw = lq;   // quarter-wave id within wave
    #pragma unroll 1
    for (int pass = 0; pass < 8; ++pass) {
        int rl  = pass * 16 + w * 4 + qw;
        int row = bT + i0 + rl;
        float4 av = *(const float4*)(xT + (size_t)row * 64 + lr * 4);
        int jown = jcand[rl * 8 + (lr & 7)];
        float D0 = INF, D1 = INF, D2 = INF;
        int   I0 = 0x7FFFFFFF, I1 = 0x7FFFFFFF, I2 = 0x7FFFFFFF;
        #pragma unroll
        for (int t = 0; t < 8; ++t) {
            int jt = __shfl(jown, (l & 48) + t, 64);
            float4 bv = *(const float4*)(xT + (size_t)(bT + jt) * 64 + lr * 4);
            float p = fmaf(bv.w, av.w, fmaf(bv.z, av.z, fmaf(bv.y, av.y, bv.x * av.x)));
            p += __shfl_xor(p, 1, 64);
            p += __shfl_xor(p, 2, 64);
            p += __shfl_xor(p, 4, 64);
            p += __shfl_xor(p, 8, 64);
            float s = nsq[bT + jt] - 2.f * p;
            bool lt2 = (s < D2) || (s == D2 && jt < I2);
            bool lt1 = (s < D1) || (s == D1 && jt < I1);
            bool lt0 = (s < D0) || (s == D0 && jt < I0);
            float nD2 = lt1 ? D1 : (lt2 ? s : D2); int nI2 = lt1 ? I1 : (lt2 ? jt : I2);
            float nD1 = lt0 ? D0 : (lt1 ? s : D1); int nI1 = lt0 ? I0 : (lt1 ? jt : I1);
            D2 = nD2; I2 = nI2; D1 = nD1; I1 = nI1;
            D0 = lt0 ? s : D0; I0 = lt0 ? jt : I0;
        }
        if (lr == 0) {
            jsel3[rl * 3 + 0] = I0; jsel3[rl * 3 + 1] = I1; jsel3[rl * 3 + 2] = I2;
        }
    }
    __syncthreads();

    // --- Phase C: conv in 4 sub-tiles of 32 rows (fmaf chain identical to R7).
    #pragma unroll 1
    for (int st = 0; st < 4; ++st) {
        if (tid < 96) {
            int k  = tid >> 5;
            int ip = tid & 31;
            int j  = jsel3[(st * 32 + ip) * 3 + k];
            const float4* src = (const float4*)(xT + (size_t)(bT + j) * 64);
            #pragma unroll
            for (int c4 = 0; c4 < 16; ++c4) {
                float4 v = src[c4];
                int mm = k * 64 + c4 * 4;
                g_s[(mm + 0) * 32 + ip] = v.x;
                g_s[(mm + 1) * 32 + ip] = v.y;
                g_s[(mm + 2) * 32 + ip] = v.z;
                g_s[(mm + 3) * 32 + ip] = v.w;
            }
        }
        __syncthreads();

        int oq = tid >> 4;        // o = oq*4 .. +3
        int iq = tid & 15;        // i' = iq*2, +1
        float a0x = 0.f, a0y = 0.f, a1x = 0.f, a1y = 0.f;
        float a2x = 0.f, a2y = 0.f, a3x = 0.f, a3y = 0.f;
        #pragma unroll 4
        for (int mm = 0; mm < 192; ++mm) {
            float4 wv = *(const float4*)(Wt + mm * 64 + oq * 4);
            float2 gv = *(const float2*)(g_s + mm * 32 + iq * 2);
            a0x = fmaf(wv.x, gv.x, a0x); a0y = fmaf(wv.x, gv.y, a0y);
            a1x = fmaf(wv.y, gv.x, a1x); a1y = fmaf(wv.y, gv.y, a1y);
            a2x = fmaf(wv.z, gv.x, a2x); a2y = fmaf(wv.z, gv.y, a2y);
            a3x = fmaf(wv.w, gv.x, a3x); a3y = fmaf(wv.w, gv.y, a3y);
        }
        int o0 = oq * 4;
        float b0 = bias[o0], b1 = bias[o0 + 1], b2 = bias[o0 + 2], b3 = bias[o0 + 3];
        float2 r0; r0.x = a0x + b0; r0.y = a0y + b0;
        float2 r1; r1.x = a1x + b1; r1.y = a1y + b1;
        float2 r2; r2.x = a2x + b2; r2.y = a2y + b2;
        float2 r3; r3.x = a3x + b3; r3.y = a3y + b3;
        size_t ob = (size_t)(b * O_ + o0) * T_ + i0 + st * 32 + iq * 2;
        *(float2*)(out + ob)          = r0;
        *(float2*)(out + ob + T_)     = r1;
        *(float2*)(out + ob + 2 * T_) = r2;
        *(float2*)(out + ob + 3 * T_) = r3;
        __syncthreads();          // protect g_s before next sub-tile's gather
    }
    #undef ISSUE_DMA
}

// ---------------------------------------------------------------------------
extern "C" void kernel_launch(void* const* d_in, const int* in_sizes, int n_in,
                              void* d_out, int out_size, void* d_ws, size_t ws_size,
                              hipStream_t stream) {
    const float* x    = (const float*)d_in[0];
    const float* W    = (const float*)d_in[1];
    const float* bias = (const float*)d_in[2];
    float* out = (float*)d_out;
    float* ws  = (float*)d_ws;
    // requires ~16.8 MB workspace

    prep_kernel<<<B_ * (T_ / 64) + 48, 256, 0, stream>>>(x, W, ws);
    mega_kernel<<<256, 256, 0, stream>>>(ws, bias, out);
}

// Round 9
// 177.459 us; speedup vs baseline: 1.0345x; 1.0345x over previous
//
#include <hip/hip_runtime.h>

// Problem constants (fixed by reference)
#define B_ 16
#define C_ 64
#define T_ 2048
#define O_ 64
#define KNN 3
#define HSPLIT 4
#define JCH (T_ / HSPLIT)     // 512 j per (b,h) chunk

typedef short short8   __attribute__((ext_vector_type(8)));   // 8 bf16
typedef float f32x4    __attribute__((ext_vector_type(4)));
typedef unsigned short ushortx4 __attribute__((ext_vector_type(4)));

// Workspace layout (float slots). Total ~18 MB.
#define XT_OFF 0                              // fp32 xT[b][t][c]          : B*T*64
#define XS_OFF (XT_OFF + B_ * T_ * C_)        // ushort xs[b][t][128] hi|lo
#define NSQ_OFF (XS_OFF + B_ * T_ * C_)       // fp32 nsq[b*T+t]
#define WT_OFF (NSQ_OFF + B_ * T_)            // fp32 Wt[m][o], m=k*64+c   : 192*64
#define CAND_OFF (WT_OFF + 192 * O_)          // ushort cand[B*T][16]

__device__ inline ushort bf16_rne(float f) {
    union { float f; unsigned u; } cv; cv.f = f;
    unsigned u = cv.u;
    u += 0x7FFF + ((u >> 16) & 1);
    return (ushort)(u >> 16);
}
__device__ inline float bf16_val(ushort h) {
    union { unsigned u; float f; } cv; cv.u = ((unsigned)h) << 16; return cv.f;
}

// ---------------------------------------------------------------------------
// Prep (validated R4-R8): x (B,C,T) -> xT (B,T,C) fp32, xs bf16 [hi|lo], nsq,
//       W (O,C,K) -> Wt[k*64+c][o]
// ---------------------------------------------------------------------------
__global__ __launch_bounds__(256) void prep_kernel(const float* __restrict__ x,
                                                   const float* __restrict__ W,
                                                   float* __restrict__ ws) {
    float*  xT  = ws + XT_OFF;
    ushort* xs  = (ushort*)(ws + XS_OFF);
    float*  nsq = ws + NSQ_OFF;
    float*  Wt  = ws + WT_OFF;
    int blk = blockIdx.x;
    int tid = threadIdx.x;
    if (blk < B_ * (T_ / 64)) {
        int b  = blk / (T_ / 64);
        int t0 = (blk % (T_ / 64)) * 64;
        __shared__ float tl[64 * 65];
        #pragma unroll
        for (int r = 0; r < 16; ++r) {
            int e = r * 256 + tid;
            int c = e >> 6, t = e & 63;
            tl[c * 65 + t] = x[(b * C_ + c) * T_ + t0 + t];
        }
        __syncthreads();
        #pragma unroll
        for (int r = 0; r < 16; ++r) {
            int e = r * 256 + tid;
            int t = e >> 6, c = e & 63;
            float v = tl[c * 65 + t];
            size_t rowg = (size_t)(b * T_ + t0 + t);
            xT[rowg * 64 + c] = v;
            ushort hi = bf16_rne(v);
            float  fr = v - bf16_val(hi);
            ushort lo = bf16_rne(fr);
            xs[rowg * 128 + c]      = hi;
            xs[rowg * 128 + 64 + c] = lo;
        }
        if (tid < 64) {
            float s = 0.f;
            #pragma unroll
            for (int c = 0; c < 64; ++c) { float v = tl[c * 65 + tid]; s = fmaf(v, v, s); }
            nsq[b * T_ + t0 + tid] = s;
        }
    } else {
        int e = (blk - B_ * (T_ / 64)) * 256 + tid;
        if (e < O_ * C_ * KNN) {
            int o = e / (C_ * KNN);
            int c = (e / KNN) % C_;
            int k = e % KNN;
            Wt[(k * 64 + c) * O_ + o] = W[e];
        }
    }
}

// ---------------------------------------------------------------------------
// KNN screen v4: NO staging, NO per-round barriers. A-operands read directly
// from global (L1/L2-resident: 4 waves/block share j-tiles; XCD gets ~1 MB of
// xs). Waves free-run over 32 16-j tiles; 16 waves/CU hide VMEM latency.
// Same score bits as R6/R7 (identical MFMA chains + 10-bit id packing) ->
// screen semantics unchanged. Epilogue (validated R6): merge 4 lq-stripes ->
// top-4 per (row, quarter); 16 cands/row total. Only 2 barriers in kernel.
// ---------------------------------------------------------------------------
__global__ __launch_bounds__(256, 4) void knn_mfma_kernel(const ushort* __restrict__ xs,
                                                          const float* __restrict__ nsq,
                                                          ushort* __restrict__ cand) {
    __shared__ float nsqs[JCH];        // 2 KB
    __shared__ float fbuf[128 * 16];   // 8 KB merge buffer

    int bid = blockIdx.x;
    int g   = bid & 63;                 // group = b*4 + h
    int m   = bid >> 6;                 // i-tile 0..15 (128 rows each)
    int b   = g >> 2, h = g & 3;
    int i0  = m * 128;
    int tid = threadIdx.x;
    int w   = tid >> 6, l = tid & 63, lr = l & 15, lq = l >> 4;
    const ushort* xsb = xs + (size_t)b * T_ * 128;
    int jBase = h * JCH;
    int bT = b * T_;

    ((float2*)nsqs)[tid] = ((const float2*)(nsq + bT + jBase))[tid];

    // B-operand frags for 2 i-sets: rows i0+w*32+lr (A) and +16 (B)
    short8 bA0, bA1, bA4, bA5, bB0, bB1, bB4, bB5;
    {
        const ushort* ia = xsb + (size_t)(i0 + w * 32 + lr) * 128 + lq * 8;
        bA0 = *(const short8*)(ia + 0);  bA1 = *(const short8*)(ia + 32);
        bA4 = *(const short8*)(ia + 64); bA5 = *(const short8*)(ia + 96);
        const ushort* ib2 = ia + 16 * 128;
        bB0 = *(const short8*)(ib2 + 0);  bB1 = *(const short8*)(ib2 + 32);
        bB4 = *(const short8*)(ib2 + 64); bB5 = *(const short8*)(ib2 + 96);
    }
    float niA = nsq[bT + i0 + w * 32 + lr] + 4.0f;
    float niB = nsq[bT + i0 + w * 32 + 16 + lr] + 4.0f;

    const float INF = __builtin_inff();
    float kA0 = INF, kA1 = INF, kA2 = INF, kA3 = INF;
    float kB0 = INF, kB1 = INF, kB2 = INF, kB3 = INF;

    __syncthreads();                   // nsqs visible

    #pragma unroll 2
    for (int jt16 = 0; jt16 < JCH / 16; ++jt16) {
        // A-operand directly from global: lane (lr,lq) reads row jBase+jt16*16+lr,
        // 16B chunks at lq*16 / +64 / +128 / +192 (same elements as R7's LDS path)
        const ushort* ar = xsb + (size_t)(jBase + jt16 * 16 + lr) * 128 + lq * 8;
        short8 ah0 = *(const short8*)(ar + 0);
        short8 ah1 = *(const short8*)(ar + 32);
        short8 al0 = *(const short8*)(ar + 64);
        short8 al1 = *(const short8*)(ar + 96);
        f32x4 accA = {0.f, 0.f, 0.f, 0.f};
        f32x4 accB = {0.f, 0.f, 0.f, 0.f};
        accA = __builtin_amdgcn_mfma_f32_16x16x32_bf16(ah0, bA0, accA, 0, 0, 0);
        accB = __builtin_amdgcn_mfma_f32_16x16x32_bf16(ah0, bB0, accB, 0, 0, 0);
        accA = __builtin_amdgcn_mfma_f32_16x16x32_bf16(ah1, bA1, accA, 0, 0, 0);
        accB = __builtin_amdgcn_mfma_f32_16x16x32_bf16(ah1, bB1, accB, 0, 0, 0);
        accA = __builtin_amdgcn_mfma_f32_16x16x32_bf16(al0, bA0, accA, 0, 0, 0);
        accB = __builtin_amdgcn_mfma_f32_16x16x32_bf16(al0, bB0, accB, 0, 0, 0);
        accA = __builtin_amdgcn_mfma_f32_16x16x32_bf16(al1, bA1, accA, 0, 0, 0);
        accB = __builtin_amdgcn_mfma_f32_16x16x32_bf16(al1, bB1, accB, 0, 0, 0);
        accA = __builtin_amdgcn_mfma_f32_16x16x32_bf16(ah0, bA4, accA, 0, 0, 0);
        accB = __builtin_amdgcn_mfma_f32_16x16x32_bf16(ah0, bB4, accB, 0, 0, 0);
        accA = __builtin_amdgcn_mfma_f32_16x16x32_bf16(ah1, bA5, accA, 0, 0, 0);
        accB = __builtin_amdgcn_mfma_f32_16x16x32_bf16(ah1, bB5, accB, 0, 0, 0);
        float4 nv = *(const float4*)(nsqs + jt16 * 16 + lq * 4);
        int idb = (jt16 << 2) | (lq << 8);          // 10-bit id base (R6 scheme)
        #define INS(K0, K1, K2, K3, sv, idv) {                                  \
            unsigned uu = (__float_as_uint(sv) & 0xFFFFFC00u) | (unsigned)(idv); \
            float kf = __uint_as_float(uu);                                      \
            float n0 = fminf(K0, kf);                                            \
            float n1 = __builtin_amdgcn_fmed3f(K0, K1, kf);                      \
            float n2 = __builtin_amdgcn_fmed3f(K1, K2, kf);                      \
            float n3 = __builtin_amdgcn_fmed3f(K2, K3, kf);                      \
            K0 = n0; K1 = n1; K2 = n2; K3 = n3; }
        {
            float s0 = fmaf(-2.f, accA[0], nv.x + niA); INS(kA0, kA1, kA2, kA3, s0, idb + 0);
            float s1 = fmaf(-2.f, accA[1], nv.y + niA); INS(kA0, kA1, kA2, kA3, s1, idb + 1);
            float s2 = fmaf(-2.f, accA[2], nv.z + niA); INS(kA0, kA1, kA2, kA3, s2, idb + 2);
            float s3 = fmaf(-2.f, accA[3], nv.w + niA); INS(kA0, kA1, kA2, kA3, s3, idb + 3);
        }
        {
            float s0 = fmaf(-2.f, accB[0], nv.x + niB); INS(kB0, kB1, kB2, kB3, s0, idb + 0);
            float s1 = fmaf(-2.f, accB[1], nv.y + niB); INS(kB0, kB1, kB2, kB3, s1, idb + 1);
            float s2 = fmaf(-2.f, accB[2], nv.z + niB); INS(kB0, kB1, kB2, kB3, s2, idb + 2);
            float s3 = fmaf(-2.f, accB[3], nv.w + niB); INS(kB0, kB1, kB2, kB3, s3, idb + 3);
        }
        #undef INS
    }

    // Epilogue (validated R6): merge 4 lq-stripes per row -> top-4, decode.
    __syncthreads();
    {
        float* pa = fbuf + (w * 32 + lr) * 16 + lq * 4;
        pa[0] = kA0; pa[1] = kA1; pa[2] = kA2; pa[3] = kA3;
        float* pb = fbuf + (w * 32 + 16 + lr) * 16 + lq * 4;
        pb[0] = kB0; pb[1] = kB1; pb[2] = kB2; pb[3] = kB3;
    }
    __syncthreads();
    if (l < 32) {
        int rloc = w * 32 + l;
        const float* pr = fbuf + rloc * 16;
        float m0 = INF, m1 = INF, m2 = INF, m3 = INF;
        #pragma unroll
        for (int q2 = 0; q2 < 16; ++q2) {
            float kf = pr[q2];
            float n0 = fminf(m0, kf);
            float n1 = __builtin_amdgcn_fmed3f(m0, m1, kf);
            float n2 = __builtin_amdgcn_fmed3f(m1, m2, kf);
            float n3 = __builtin_amdgcn_fmed3f(m2, m3, kf);
            m0 = n0; m1 = n1; m2 = n2; m3 = n3;
        }
        ushortx4 cv;
        #define DEC(mf, slot) { unsigned u = __float_as_uint(mf) & 1023u;            \
            cv[slot] = (ushort)(jBase + (((u >> 2) & 63u) << 4) + ((u >> 8) << 2) + (u & 3)); }
        DEC(m0, 0); DEC(m1, 1); DEC(m2, 2); DEC(m3, 3);
        #undef DEC
        int row = bT + i0 + rloc;
        *(ushortx4*)(cand + (size_t)row * 16 + h * 4) = cv;
    }
}

// ---------------------------------------------------------------------------
// Fused refine + gather + conv (R7 structure, 16 cands via R6's validated
// butterfly). Block = (b, 32-i tile), 256 thr, 1024 blocks (4/CU).
// ---------------------------------------------------------------------------
__global__ __launch_bounds__(256, 4) void conv_fused_kernel(const float* __restrict__ ws,
                                                            const float* __restrict__ bias,
                                                            float* __restrict__ out) {
    const float*  xT   = ws + XT_OFF;
    const float*  nsq  = ws + NSQ_OFF;
    const float*  Wt   = ws + WT_OFF;
    const ushort* cand = (const ushort*)(ws + CAND_OFF);

    __shared__ float g_s[192 * 32];
    __shared__ int   jsel3[32 * 3];

    int bb  = blockIdx.x >> 6;
    int i0  = (blockIdx.x & 63) * 32;
    int tid = threadIdx.x;
    int w = tid >> 6, l = tid & 63, qw = l >> 4, lr = l & 15;
    int bT = bb * T_;

    // --- Phase 1: exact fp32 refine over 16 cands (R6-validated butterfly)
    const float INF = __builtin_inff();
    #pragma unroll
    for (int it = 0; it < 2; ++it) {
        int rl  = w * 8 + it * 4 + qw;
        int row = bT + i0 + rl;
        float4 av = *(const float4*)(xT + (size_t)row * 64 + lr * 4);
        int jown = cand[(size_t)row * 16 + lr];
        float D0 = INF, D1 = INF, D2 = INF;
        int   I0 = 0x7FFFFFFF, I1 = 0x7FFFFFFF, I2 = 0x7FFFFFFF;
        #pragma unroll
        for (int t = 0; t < 16; ++t) {
            int jt = __shfl(jown, (l & 48) + t, 64);
            float4 bv = *(const float4*)(xT + (size_t)(bT + jt) * 64 + lr * 4);
            float p = fmaf(bv.w, av.w, fmaf(bv.z, av.z, fmaf(bv.y, av.y, bv.x * av.x)));
            p += __shfl_xor(p, 1, 64);
            p += __shfl_xor(p, 2, 64);
            p += __shfl_xor(p, 4, 64);
            p += __shfl_xor(p, 8, 64);
            float s = nsq[bT + jt] - 2.f * p;
            bool lt2 = (s < D2) || (s == D2 && jt < I2);
            bool lt1 = (s < D1) || (s == D1 && jt < I1);
            bool lt0 = (s < D0) || (s == D0 && jt < I0);
            float nD2 = lt1 ? D1 : (lt2 ? s : D2); int nI2 = lt1 ? I1 : (lt2 ? jt : I2);
            float nD1 = lt0 ? D0 : (lt1 ? s : D1); int nI1 = lt0 ? I0 : (lt1 ? jt : I1);
            D2 = nD2; I2 = nI2; D1 = nD1; I1 = nI1;
            D0 = lt0 ? s : D0; I0 = lt0 ? jt : I0;
        }
        if (lr == 0) {
            jsel3[rl * 3 + 0] = I0; jsel3[rl * 3 + 1] = I1; jsel3[rl * 3 + 2] = I2;
        }
    }
    __syncthreads();

    // --- Phase 2: gather 3 neighbor rows per i' -> g_s[m][i']
    if (tid < 96) {
        int k  = tid >> 5;
        int ip = tid & 31;
        int j  = jsel3[ip * 3 + k];
        const float4* src = (const float4*)(xT + (size_t)(bT + j) * 64);
        #pragma unroll
        for (int c4 = 0; c4 < 16; ++c4) {
            float4 v = src[c4];
            int mm = k * 64 + c4 * 4;
            g_s[(mm + 0) * 32 + ip] = v.x;
            g_s[(mm + 1) * 32 + ip] = v.y;
            g_s[(mm + 2) * 32 + ip] = v.z;
            g_s[(mm + 3) * 32 + ip] = v.w;
        }
    }
    __syncthreads();

    // --- Phase 3: conv (bitwise-identical fmaf chain to R6/R7/R8)
    int oq = tid >> 4;        // o = oq*4 .. +3
    int iq = tid & 15;        // i' = iq*2, +1
    float a0x = 0.f, a0y = 0.f, a1x = 0.f, a1y = 0.f;
    float a2x = 0.f, a2y = 0.f, a3x = 0.f, a3y = 0.f;
    #pragma unroll 4
    for (int mm = 0; mm < 192; ++mm) {
        float4 wv = *(const float4*)(Wt + mm * 64 + oq * 4);
        float2 gv = *(const float2*)(g_s + mm * 32 + iq * 2);
        a0x = fmaf(wv.x, gv.x, a0x); a0y = fmaf(wv.x, gv.y, a0y);
        a1x = fmaf(wv.y, gv.x, a1x); a1y = fmaf(wv.y, gv.y, a1y);
        a2x = fmaf(wv.z, gv.x, a2x); a2y = fmaf(wv.z, gv.y, a2y);
        a3x = fmaf(wv.w, gv.x, a3x); a3y = fmaf(wv.w, gv.y, a3y);
    }
    int o0 = oq * 4;
    float b0 = bias[o0], b1 = bias[o0 + 1], b2 = bias[o0 + 2], b3 = bias[o0 + 3];
    float2 r0; r0.x = a0x + b0; r0.y = a0y + b0;
    float2 r1; r1.x = a1x + b1; r1.y = a1y + b1;
    float2 r2; r2.x = a2x + b2; r2.y = a2y + b2;
    float2 r3; r3.x = a3x + b3; r3.y = a3y + b3;
    size_t ob = (size_t)(bb * O_ + o0) * T_ + i0 + iq * 2;
    *(float2*)(out + ob)          = r0;
    *(float2*)(out + ob + T_)     = r1;
    *(float2*)(out + ob + 2 * T_) = r2;
    *(float2*)(out + ob + 3 * T_) = r3;
}

// ---------------------------------------------------------------------------
extern "C" void kernel_launch(void* const* d_in, const int* in_sizes, int n_in,
                              void* d_out, int out_size, void* d_ws, size_t ws_size,
                              hipStream_t stream) {
    const float* x    = (const float*)d_in[0];
    const float* W    = (const float*)d_in[1];
    const float* bias = (const float*)d_in[2];
    float* out = (float*)d_out;
    float* ws  = (float*)d_ws;
    // requires ~18 MB workspace

    prep_kernel<<<B_ * (T_ / 64) + 48, 256, 0, stream>>>(x, W, ws);
    knn_mfma_kernel<<<1024, 256, 0, stream>>>(
        (const ushort*)(ws + XS_OFF), ws + NSQ_OFF, (ushort*)(ws + CAND_OFF));
    conv_fused_kernel<<<B_ * 64, 256, 0, stream>>>(ws, bias, out);
}

// Round 10
// 165.805 us; speedup vs baseline: 1.1072x; 1.0703x over previous
//
#include <hip/hip_runtime.h>

// Problem constants (fixed by reference)
#define B_ 16
#define C_ 64
#define T_ 2048
#define O_ 64
#define KNN 3
#define HSPLIT 8
#define JCH (T_ / HSPLIT)     // 256 j per (b,h) chunk

typedef short short8   __attribute__((ext_vector_type(8)));   // 8 bf16
typedef float f32x4    __attribute__((ext_vector_type(4)));
typedef unsigned short ushortx4 __attribute__((ext_vector_type(4)));

// Workspace layout (float slots). Total ~27.5 MB (<< 256 MiB ws).
#define XT_OFF 0                              // fp32 xT[b][t][c]          : B*T*64
#define XF_OFF (XT_OFF + B_ * T_ * C_)        // ushort xf[b][tile128][k4][lane64][8]
                                              //   = bf16 operands in MFMA lane order
#define NSQ_OFF (XF_OFF + B_ * T_ * C_)       // fp32 nsq[b*T+t]
#define WT_OFF (NSQ_OFF + B_ * T_)            // fp32 Wt[m][o], m=k*64+c   : 192*64
#define CAND_OFF (WT_OFF + 192 * O_)          // ushort cand[B*T][32]

__device__ inline ushort bf16_rne(float f) {
    union { float f; unsigned u; } cv; cv.f = f;
    unsigned u = cv.u;
    u += 0x7FFF + ((u >> 16) & 1);
    return (ushort)(u >> 16);
}
__device__ inline float bf16_val(ushort h) {
    union { unsigned u; float f; } cv; cv.u = ((unsigned)h) << 16; return cv.f;
}

// ---------------------------------------------------------------------------
// Prep: x (B,C,T) -> xT (B,T,C) fp32, nsq, Wt (all validated R4-R9), and
// xf = bf16 hi/lo split REORDERED into MFMA fragment lane order:
//   xf[b][tile][k][lane l] (16B) = (k<2 ? hi : lo)[(k&1)*32 + (l>>4)*8 ..+7]
//                                   of row tile*16 + (l&15)
// -> every operand load in knn is one fully-contiguous 1KB wave-load.
// Same bf16 values as R4-R9's xs (bit-identical downstream scores).
// ---------------------------------------------------------------------------
__global__ __launch_bounds__(256) void prep_kernel(const float* __restrict__ x,
                                                   const float* __restrict__ W,
                                                   float* __restrict__ ws) {
    float*  xT  = ws + XT_OFF;
    ushort* xf  = (ushort*)(ws + XF_OFF);
    float*  nsq = ws + NSQ_OFF;
    float*  Wt  = ws + WT_OFF;
    int blk = blockIdx.x;
    int tid = threadIdx.x;
    if (blk < B_ * (T_ / 64)) {
        int b  = blk / (T_ / 64);
        int t0 = (blk % (T_ / 64)) * 64;
        __shared__ float tl[64 * 65];
        #pragma unroll
        for (int r = 0; r < 16; ++r) {
            int e = r * 256 + tid;
            int c = e >> 6, t = e & 63;
            tl[c * 65 + t] = x[(b * C_ + c) * T_ + t0 + t];
        }
        __syncthreads();
        #pragma unroll
        for (int r = 0; r < 16; ++r) {
            int e = r * 256 + tid;
            int t = e >> 6, c = e & 63;
            xT[(size_t)(b * T_ + t0 + t) * 64 + c] = tl[c * 65 + t];
        }
        // xf fragment-order write: 4 tiles x 4 k x 64 lanes = 1024 16B units
        #pragma unroll
        for (int rep = 0; rep < 4; ++rep) {
            int u = rep * 256 + tid;
            int tile_l = u >> 8;            // 0..3
            int k      = (u >> 6) & 3;      // 0..3
            int l2     = u & 63;
            int lr2 = l2 & 15, lq2 = l2 >> 4;
            int trow = tile_l * 16 + lr2;   // row within this 64-row chunk
            int c0   = (k & 1) * 32 + lq2 * 8;
            short8 v8;
            #pragma unroll
            for (int ci = 0; ci < 8; ++ci) {
                float v = tl[(c0 + ci) * 65 + trow];
                ushort hi = bf16_rne(v);
                v8[ci] = (k < 2) ? (short)hi : (short)bf16_rne(v - bf16_val(hi));
            }
            size_t tileG = (size_t)b * 128 + (t0 >> 4) + tile_l;
            *(short8*)(xf + ((tileG * 4 + k) * 64 + l2) * 8) = v8;
        }
        if (tid < 64) {
            float s = 0.f;
            #pragma unroll
            for (int c = 0; c < 64; ++c) { float v = tl[c * 65 + tid]; s = fmaf(v, v, s); }
            nsq[b * T_ + t0 + tid] = s;
        }
    } else {
        int e = (blk - B_ * (T_ / 64)) * 256 + tid;
        if (e < O_ * C_ * KNN) {
            int o = e / (C_ * KNN);
            int c = (e / KNN) % C_;
            int k = e % KNN;
            Wt[(k * 64 + c) * O_ + o] = W[e];
        }
    }
}

// ---------------------------------------------------------------------------
// KNN screen v5: operands from xf -> every A/B-frag load is one contiguous
// 1KB wave-load (lane l at l*16B). No LDS staging, no per-round barriers;
// waves free-run. HSPLIT=8 -> 2048 blocks = 8/CU (grid was the occupancy
// cap in R9). Score bits identical to R6-R9 (same values, same MFMA chain).
// Epilogue (validated R6): merge 4 lq-stripes -> top-4 per (row, chunk);
// 32 cands/row total.
// ---------------------------------------------------------------------------
__global__ __launch_bounds__(256, 4) void knn_mfma_kernel(const ushort* __restrict__ xf,
                                                          const float* __restrict__ nsq,
                                                          ushort* __restrict__ cand) {
    __shared__ float nsqs[JCH];        // 1 KB
    __shared__ float fbuf[128 * 16];   // 8 KB merge buffer

    int bid = blockIdx.x;
    int g   = bid & 127;                // group = b*8 + h (same-(b,h) -> same XCD)
    int m   = bid >> 7;                 // i-tile 0..15 (128 rows each)
    int b   = g >> 3, h = g & 7;
    int i0  = m * 128;
    int tid = threadIdx.x;
    int w   = tid >> 6, l = tid & 63, lr = l & 15, lq = l >> 4;
    const ushort* xfb = xf + (size_t)b * T_ * 128;   // 128 tiles * 4 * 512
    int jBase = h * JCH;
    int bT = b * T_;

    nsqs[tid] = nsq[bT + jBase + tid];

    // B-operand frags from xf: tiles (i0/16 + w*2) and +1, one 1KB load each
    short8 bA0, bA1, bA4, bA5, bB0, bB1, bB4, bB5;
    {
        const ushort* pA = xfb + (size_t)(i0 / 16 + w * 2) * 4 * 512 + l * 8;
        bA0 = *(const short8*)(pA + 0 * 512);
        bA1 = *(const short8*)(pA + 1 * 512);
        bA4 = *(const short8*)(pA + 2 * 512);
        bA5 = *(const short8*)(pA + 3 * 512);
        const ushort* pB = pA + 4 * 512;
        bB0 = *(const short8*)(pB + 0 * 512);
        bB1 = *(const short8*)(pB + 1 * 512);
        bB4 = *(const short8*)(pB + 2 * 512);
        bB5 = *(const short8*)(pB + 3 * 512);
    }
    float niA = nsq[bT + i0 + w * 32 + lr] + 4.0f;
    float niB = nsq[bT + i0 + w * 32 + 16 + lr] + 4.0f;

    const float INF = __builtin_inff();
    float kA0 = INF, kA1 = INF, kA2 = INF, kA3 = INF;
    float kB0 = INF, kB1 = INF, kB2 = INF, kB3 = INF;

    __syncthreads();                   // nsqs visible

    #pragma unroll 2
    for (int jt16 = 0; jt16 < JCH / 16; ++jt16) {
        const ushort* par = xfb + (size_t)(h * (JCH / 16) + jt16) * 4 * 512 + l * 8;
        short8 ah0 = *(const short8*)(par + 0 * 512);   // contiguous 1KB wave-load
        short8 ah1 = *(const short8*)(par + 1 * 512);
        short8 al0 = *(const short8*)(par + 2 * 512);
        short8 al1 = *(const short8*)(par + 3 * 512);
        f32x4 accA = {0.f, 0.f, 0.f, 0.f};
        f32x4 accB = {0.f, 0.f, 0.f, 0.f};
        accA = __builtin_amdgcn_mfma_f32_16x16x32_bf16(ah0, bA0, accA, 0, 0, 0);
        accB = __builtin_amdgcn_mfma_f32_16x16x32_bf16(ah0, bB0, accB, 0, 0, 0);
        accA = __builtin_amdgcn_mfma_f32_16x16x32_bf16(ah1, bA1, accA, 0, 0, 0);
        accB = __builtin_amdgcn_mfma_f32_16x16x32_bf16(ah1, bB1, accB, 0, 0, 0);
        accA = __builtin_amdgcn_mfma_f32_16x16x32_bf16(al0, bA0, accA, 0, 0, 0);
        accB = __builtin_amdgcn_mfma_f32_16x16x32_bf16(al0, bB0, accB, 0, 0, 0);
        accA = __builtin_amdgcn_mfma_f32_16x16x32_bf16(al1, bA1, accA, 0, 0, 0);
        accB = __builtin_amdgcn_mfma_f32_16x16x32_bf16(al1, bB1, accB, 0, 0, 0);
        accA = __builtin_amdgcn_mfma_f32_16x16x32_bf16(ah0, bA4, accA, 0, 0, 0);
        accB = __builtin_amdgcn_mfma_f32_16x16x32_bf16(ah0, bB4, accB, 0, 0, 0);
        accA = __builtin_amdgcn_mfma_f32_16x16x32_bf16(ah1, bA5, accA, 0, 0, 0);
        accB = __builtin_amdgcn_mfma_f32_16x16x32_bf16(ah1, bB5, accB, 0, 0, 0);
        float4 nv = *(const float4*)(nsqs + jt16 * 16 + lq * 4);
        int idb = (jt16 << 2) | (lq << 8);          // 10-bit id (R6 scheme)
        #define INS(K0, K1, K2, K3, sv, idv) {                                  \
            unsigned uu = (__float_as_uint(sv) & 0xFFFFFC00u) | (unsigned)(idv); \
            float kf = __uint_as_float(uu);                                      \
            float n0 = fminf(K0, kf);                                            \
            float n1 = __builtin_amdgcn_fmed3f(K0, K1, kf);                      \
            float n2 = __builtin_amdgcn_fmed3f(K1, K2, kf);                      \
            float n3 = __builtin_amdgcn_fmed3f(K2, K3, kf);                      \
            K0 = n0; K1 = n1; K2 = n2; K3 = n3; }
        {
            float s0 = fmaf(-2.f, accA[0], nv.x + niA); INS(kA0, kA1, kA2, kA3, s0, idb + 0);
            float s1 = fmaf(-2.f, accA[1], nv.y + niA); INS(kA0, kA1, kA2, kA3, s1, idb + 1);
            float s2 = fmaf(-2.f, accA[2], nv.z + niA); INS(kA0, kA1, kA2, kA3, s2, idb + 2);
            float s3 = fmaf(-2.f, accA[3], nv.w + niA); INS(kA0, kA1, kA2, kA3, s3, idb + 3);
        }
        {
            float s0 = fmaf(-2.f, accB[0], nv.x + niB); INS(kB0, kB1, kB2, kB3, s0, idb + 0);
            float s1 = fmaf(-2.f, accB[1], nv.y + niB); INS(kB0, kB1, kB2, kB3, s1, idb + 1);
            float s2 = fmaf(-2.f, accB[2], nv.z + niB); INS(kB0, kB1, kB2, kB3, s2, idb + 2);
            float s3 = fmaf(-2.f, accB[3], nv.w + niB); INS(kB0, kB1, kB2, kB3, s3, idb + 3);
        }
        #undef INS
    }

    // Epilogue (validated R6): merge 4 lq-stripes per row -> top-4, decode.
    __syncthreads();
    {
        float* pa = fbuf + (w * 32 + lr) * 16 + lq * 4;
        pa[0] = kA0; pa[1] = kA1; pa[2] = kA2; pa[3] = kA3;
        float* pb = fbuf + (w * 32 + 16 + lr) * 16 + lq * 4;
        pb[0] = kB0; pb[1] = kB1; pb[2] = kB2; pb[3] = kB3;
    }
    __syncthreads();
    if (l < 32) {
        int rloc = w * 32 + l;
        const float* pr = fbuf + rloc * 16;
        float m0 = INF, m1 = INF, m2 = INF, m3 = INF;
        #pragma unroll
        for (int q2 = 0; q2 < 16; ++q2) {
            float kf = pr[q2];
            float n0 = fminf(m0, kf);
            float n1 = __builtin_amdgcn_fmed3f(m0, m1, kf);
            float n2 = __builtin_amdgcn_fmed3f(m1, m2, kf);
            float n3 = __builtin_amdgcn_fmed3f(m2, m3, kf);
            m0 = n0; m1 = n1; m2 = n2; m3 = n3;
        }
        ushortx4 cv;
        #define DEC(mf, slot) { unsigned u = __float_as_uint(mf) & 1023u;            \
            cv[slot] = (ushort)(jBase + (((u >> 2) & 63u) << 4) + ((u >> 8) << 2) + (u & 3)); }
        DEC(m0, 0); DEC(m1, 1); DEC(m2, 2); DEC(m3, 3);
        #undef DEC
        int row = bT + i0 + rloc;
        *(ushortx4*)(cand + (size_t)row * 32 + h * 4) = cv;
    }
}

// ---------------------------------------------------------------------------
// Fused refine + gather + conv (validated structure; refine widened to 32
// cands via the R6 butterfly). Block = (b, 32-i tile), 256 thr, 1024 blocks.
// ---------------------------------------------------------------------------
__global__ __launch_bounds__(256, 4) void conv_fused_kernel(const float* __restrict__ ws,
                                                            const float* __restrict__ bias,
                                                            float* __restrict__ out) {
    const float*  xT   = ws + XT_OFF;
    const float*  nsq  = ws + NSQ_OFF;
    const float*  Wt   = ws + WT_OFF;
    const ushort* cand = (const ushort*)(ws + CAND_OFF);

    __shared__ float g_s[192 * 32];
    __shared__ int   jsel3[32 * 3];

    int bb  = blockIdx.x >> 6;
    int i0  = (blockIdx.x & 63) * 32;
    int tid = threadIdx.x;
    int w = tid >> 6, l = tid & 63, qw = l >> 4, lr = l & 15;
    int bT = bb * T_;

    // --- Phase 1: exact fp32 refine over 32 cands (R6-validated butterfly)
    const float INF = __builtin_inff();
    #pragma unroll
    for (int it = 0; it < 2; ++it) {
        int rl  = w * 8 + it * 4 + qw;
        int row = bT + i0 + rl;
        float4 av = *(const float4*)(xT + (size_t)row * 64 + lr * 4);
        int jown0 = cand[(size_t)row * 32 + lr];
        int jown1 = cand[(size_t)row * 32 + 16 + lr];
        float D0 = INF, D1 = INF, D2 = INF;
        int   I0 = 0x7FFFFFFF, I1 = 0x7FFFFFFF, I2 = 0x7FFFFFFF;
        #pragma unroll
        for (int t = 0; t < 32; ++t) {
            int jt = __shfl((t < 16) ? jown0 : jown1, (l & 48) + (t & 15), 64);
            float4 bv = *(const float4*)(xT + (size_t)(bT + jt) * 64 + lr * 4);
            float p = fmaf(bv.w, av.w, fmaf(bv.z, av.z, fmaf(bv.y, av.y, bv.x * av.x)));
            p += __shfl_xor(p, 1, 64);
            p += __shfl_xor(p, 2, 64);
            p += __shfl_xor(p, 4, 64);
            p += __shfl_xor(p, 8, 64);
            float s = nsq[bT + jt] - 2.f * p;
            bool lt2 = (s < D2) || (s == D2 && jt < I2);
            bool lt1 = (s < D1) || (s == D1 && jt < I1);
            bool lt0 = (s < D0) || (s == D0 && jt < I0);
            float nD2 = lt1 ? D1 : (lt2 ? s : D2); int nI2 = lt1 ? I1 : (lt2 ? jt : I2);
            float nD1 = lt0 ? D0 : (lt1 ? s : D1); int nI1 = lt0 ? I0 : (lt1 ? jt : I1);
            D2 = nD2; I2 = nI2; D1 = nD1; I1 = nI1;
            D0 = lt0 ? s : D0; I0 = lt0 ? jt : I0;
        }
        if (lr == 0) {
            jsel3[rl * 3 + 0] = I0; jsel3[rl * 3 + 1] = I1; jsel3[rl * 3 + 2] = I2;
        }
    }
    __syncthreads();

    // --- Phase 2: gather 3 neighbor rows per i' -> g_s[m][i']
    if (tid < 96) {
        int k  = tid >> 5;
        int ip = tid & 31;
        int j  = jsel3[ip * 3 + k];
        const float4* src = (const float4*)(xT + (size_t)(bT + j) * 64);
        #pragma unroll
        for (int c4 = 0; c4 < 16; ++c4) {
            float4 v = src[c4];
            int mm = k * 64 + c4 * 4;
            g_s[(mm + 0) * 32 + ip] = v.x;
            g_s[(mm + 1) * 32 + ip] = v.y;
            g_s[(mm + 2) * 32 + ip] = v.z;
            g_s[(mm + 3) * 32 + ip] = v.w;
        }
    }
    __syncthreads();

    // --- Phase 3: conv (bitwise-identical fmaf chain to R6-R9)
    int oq = tid >> 4;        // o = oq*4 .. +3
    int iq = tid & 15;        // i' = iq*2, +1
    float a0x = 0.f, a0y = 0.f, a1x = 0.f, a1y = 0.f;
    float a2x = 0.f, a2y = 0.f, a3x = 0.f, a3y = 0.f;
    #pragma unroll 4
    for (int mm = 0; mm < 192; ++mm) {
        float4 wv = *(const float4*)(Wt + mm * 64 + oq * 4);
        float2 gv = *(const float2*)(g_s + mm * 32 + iq * 2);
        a0x = fmaf(wv.x, gv.x, a0x); a0y = fmaf(wv.x, gv.y, a0y);
        a1x = fmaf(wv.y, gv.x, a1x); a1y = fmaf(wv.y, gv.y, a1y);
        a2x = fmaf(wv.z, gv.x, a2x); a2y = fmaf(wv.z, gv.y, a2y);
        a3x = fmaf(wv.w, gv.x, a3x); a3y = fmaf(wv.w, gv.y, a3y);
    }
    int o0 = oq * 4;
    float b0 = bias[o0], b1 = bias[o0 + 1], b2 = bias[o0 + 2], b3 = bias[o0 + 3];
    float2 r0; r0.x = a0x + b0; r0.y = a0y + b0;
    float2 r1; r1.x = a1x + b1; r1.y = a1y + b1;
    float2 r2; r2.x = a2x + b2; r2.y = a2y + b2;
    float2 r3; r3.x = a3x + b3; r3.y = a3y + b3;
    size_t ob = (size_t)(bb * O_ + o0) * T_ + i0 + iq * 2;
    *(float2*)(out + ob)          = r0;
    *(float2*)(out + ob + T_)     = r1;
    *(float2*)(out + ob + 2 * T_) = r2;
    *(float2*)(out + ob + 3 * T_) = r3;
}

// ---------------------------------------------------------------------------
extern "C" void kernel_launch(void* const* d_in, const int* in_sizes, int n_in,
                              void* d_out, int out_size, void* d_ws, size_t ws_size,
                              hipStream_t stream) {
    const float* x    = (const float*)d_in[0];
    const float* W    = (const float*)d_in[1];
    const float* bias = (const float*)d_in[2];
    float* out = (float*)d_out;
    float* ws  = (float*)d_ws;
    // requires ~27.5 MB workspace

    prep_kernel<<<B_ * (T_ / 64) + 48, 256, 0, stream>>>(x, W, ws);
    knn_mfma_kernel<<<2048, 256, 0, stream>>>(
        (const ushort*)(ws + XF_OFF), ws + NSQ_OFF, (ushort*)(ws + CAND_OFF));
    conv_fused_kernel<<<B_ * 64, 256, 0, stream>>>(ws, bias, out);
}

// Round 11
// 141.190 us; speedup vs baseline: 1.3002x; 1.1743x over previous
//
#include <hip/hip_runtime.h>

// Problem constants (fixed by reference)
#define B_ 16
#define C_ 64
#define T_ 2048
#define O_ 64
#define KNN 3
#define HSPLIT 8
#define JCH (T_ / HSPLIT)     // 256 j per (b,h) chunk

typedef short short8   __attribute__((ext_vector_type(8)));   // 8 bf16
typedef float f32x4    __attribute__((ext_vector_type(4)));

// Workspace layout (float slots). Total ~28 MB (<< 256 MiB ws).
#define XT_OFF 0                              // fp32 xT[b][t][c]          : B*T*64
#define XF_OFF (XT_OFF + B_ * T_ * C_)        // ushort xf[b][tile128][k4][lane64][8]
#define NSQ_OFF (XF_OFF + B_ * T_ * C_)       // fp32 nsq[b*T+t]
#define WT_OFF (NSQ_OFF + B_ * T_)            // fp32 Wt[m][o], m=k*64+c   : 192*64
#define CAND_OFF (WT_OFF + 192 * O_)          // float candf[B*T][32] packed keys (global 11-bit id)

__device__ inline ushort bf16_rne(float f) {
    union { float f; unsigned u; } cv; cv.f = f;
    unsigned u = cv.u;
    u += 0x7FFF + ((u >> 16) & 1);
    return (ushort)(u >> 16);
}
__device__ inline float bf16_val(ushort h) {
    union { unsigned u; float f; } cv; cv.u = ((unsigned)h) << 16; return cv.f;
}

// ---------------------------------------------------------------------------
// Prep (validated R9/R10): xT fp32, xf in MFMA fragment lane order, nsq, Wt.
// ---------------------------------------------------------------------------
__global__ __launch_bounds__(256) void prep_kernel(const float* __restrict__ x,
                                                   const float* __restrict__ W,
                                                   float* __restrict__ ws) {
    float*  xT  = ws + XT_OFF;
    ushort* xf  = (ushort*)(ws + XF_OFF);
    float*  nsq = ws + NSQ_OFF;
    float*  Wt  = ws + WT_OFF;
    int blk = blockIdx.x;
    int tid = threadIdx.x;
    if (blk < B_ * (T_ / 64)) {
        int b  = blk / (T_ / 64);
        int t0 = (blk % (T_ / 64)) * 64;
        __shared__ float tl[64 * 65];
        #pragma unroll
        for (int r = 0; r < 16; ++r) {
            int e = r * 256 + tid;
            int c = e >> 6, t = e & 63;
            tl[c * 65 + t] = x[(b * C_ + c) * T_ + t0 + t];
        }
        __syncthreads();
        #pragma unroll
        for (int r = 0; r < 16; ++r) {
            int e = r * 256 + tid;
            int t = e >> 6, c = e & 63;
            xT[(size_t)(b * T_ + t0 + t) * 64 + c] = tl[c * 65 + t];
        }
        // xf fragment-order write: 4 tiles x 4 k x 64 lanes = 1024 16B units
        #pragma unroll
        for (int rep = 0; rep < 4; ++rep) {
            int u = rep * 256 + tid;
            int tile_l = u >> 8;            // 0..3
            int k      = (u >> 6) & 3;      // 0..3
            int l2     = u & 63;
            int lr2 = l2 & 15, lq2 = l2 >> 4;
            int trow = tile_l * 16 + lr2;
            int c0   = (k & 1) * 32 + lq2 * 8;
            short8 v8;
            #pragma unroll
            for (int ci = 0; ci < 8; ++ci) {
                float v = tl[(c0 + ci) * 65 + trow];
                ushort hi = bf16_rne(v);
                v8[ci] = (k < 2) ? (short)hi : (short)bf16_rne(v - bf16_val(hi));
            }
            size_t tileG = (size_t)b * 128 + (t0 >> 4) + tile_l;
            *(short8*)(xf + ((tileG * 4 + k) * 64 + l2) * 8) = v8;
        }
        if (tid < 64) {
            float s = 0.f;
            #pragma unroll
            for (int c = 0; c < 64; ++c) { float v = tl[c * 65 + tid]; s = fmaf(v, v, s); }
            nsq[b * T_ + t0 + tid] = s;
        }
    } else {
        int e = (blk - B_ * (T_ / 64)) * 256 + tid;
        if (e < O_ * C_ * KNN) {
            int o = e / (C_ * KNN);
            int c = (e / KNN) % C_;
            int k = e % KNN;
            Wt[(k * 64 + c) * O_ + o] = W[e];
        }
    }
}

// ---------------------------------------------------------------------------
// KNN screen v5 (validated R10 body). Epilogue change: after the per-(row,h)
// top-4 merge, re-pack GLOBAL j into the key's low 11 bits (R8-validated
// stomp scheme) and store 4 float keys -> candf[row][h*4..]. Keys from all 8
// chunks are directly comparable (same score formula).
// ---------------------------------------------------------------------------
__global__ __launch_bounds__(256, 4) void knn_mfma_kernel(const ushort* __restrict__ xf,
                                                          const float* __restrict__ nsq,
                                                          float* __restrict__ candf) {
    __shared__ float nsqs[JCH];        // 1 KB
    __shared__ float fbuf[128 * 16];   // 8 KB merge buffer

    int bid = blockIdx.x;
    int g   = bid & 127;                // group = b*8 + h
    int m   = bid >> 7;                 // i-tile 0..15 (128 rows each)
    int b   = g >> 3, h = g & 7;
    int i0  = m * 128;
    int tid = threadIdx.x;
    int w   = tid >> 6, l = tid & 63, lr = l & 15, lq = l >> 4;
    const ushort* xfb = xf + (size_t)b * T_ * 128;
    int jBase = h * JCH;
    int bT = b * T_;

    nsqs[tid] = nsq[bT + jBase + tid];

    short8 bA0, bA1, bA4, bA5, bB0, bB1, bB4, bB5;
    {
        const ushort* pA = xfb + (size_t)(i0 / 16 + w * 2) * 4 * 512 + l * 8;
        bA0 = *(const short8*)(pA + 0 * 512);
        bA1 = *(const short8*)(pA + 1 * 512);
        bA4 = *(const short8*)(pA + 2 * 512);
        bA5 = *(const short8*)(pA + 3 * 512);
        const ushort* pB = pA + 4 * 512;
        bB0 = *(const short8*)(pB + 0 * 512);
        bB1 = *(const short8*)(pB + 1 * 512);
        bB4 = *(const short8*)(pB + 2 * 512);
        bB5 = *(const short8*)(pB + 3 * 512);
    }
    float niA = nsq[bT + i0 + w * 32 + lr] + 4.0f;
    float niB = nsq[bT + i0 + w * 32 + 16 + lr] + 4.0f;

    const float INF = __builtin_inff();
    float kA0 = INF, kA1 = INF, kA2 = INF, kA3 = INF;
    float kB0 = INF, kB1 = INF, kB2 = INF, kB3 = INF;

    __syncthreads();                   // nsqs visible

    #pragma unroll 2
    for (int jt16 = 0; jt16 < JCH / 16; ++jt16) {
        const ushort* par = xfb + (size_t)(h * (JCH / 16) + jt16) * 4 * 512 + l * 8;
        short8 ah0 = *(const short8*)(par + 0 * 512);   // contiguous 1KB wave-load
        short8 ah1 = *(const short8*)(par + 1 * 512);
        short8 al0 = *(const short8*)(par + 2 * 512);
        short8 al1 = *(const short8*)(par + 3 * 512);
        f32x4 accA = {0.f, 0.f, 0.f, 0.f};
        f32x4 accB = {0.f, 0.f, 0.f, 0.f};
        accA = __builtin_amdgcn_mfma_f32_16x16x32_bf16(ah0, bA0, accA, 0, 0, 0);
        accB = __builtin_amdgcn_mfma_f32_16x16x32_bf16(ah0, bB0, accB, 0, 0, 0);
        accA = __builtin_amdgcn_mfma_f32_16x16x32_bf16(ah1, bA1, accA, 0, 0, 0);
        accB = __builtin_amdgcn_mfma_f32_16x16x32_bf16(ah1, bB1, accB, 0, 0, 0);
        accA = __builtin_amdgcn_mfma_f32_16x16x32_bf16(al0, bA0, accA, 0, 0, 0);
        accB = __builtin_amdgcn_mfma_f32_16x16x32_bf16(al0, bB0, accB, 0, 0, 0);
        accA = __builtin_amdgcn_mfma_f32_16x16x32_bf16(al1, bA1, accA, 0, 0, 0);
        accB = __builtin_amdgcn_mfma_f32_16x16x32_bf16(al1, bB1, accB, 0, 0, 0);
        accA = __builtin_amdgcn_mfma_f32_16x16x32_bf16(ah0, bA4, accA, 0, 0, 0);
        accB = __builtin_amdgcn_mfma_f32_16x16x32_bf16(ah0, bB4, accB, 0, 0, 0);
        accA = __builtin_amdgcn_mfma_f32_16x16x32_bf16(ah1, bA5, accA, 0, 0, 0);
        accB = __builtin_amdgcn_mfma_f32_16x16x32_bf16(ah1, bB5, accB, 0, 0, 0);
        float4 nv = *(const float4*)(nsqs + jt16 * 16 + lq * 4);
        int idb = (jt16 << 2) | (lq << 8);          // 10-bit local id (R6 scheme)
        #define INS(K0, K1, K2, K3, sv, idv) {                                  \
            unsigned uu = (__float_as_uint(sv) & 0xFFFFFC00u) | (unsigned)(idv); \
            float kf = __uint_as_float(uu);                                      \
            float n0 = fminf(K0, kf);                                            \
            float n1 = __builtin_amdgcn_fmed3f(K0, K1, kf);                      \
            float n2 = __builtin_amdgcn_fmed3f(K1, K2, kf);                      \
            float n3 = __builtin_amdgcn_fmed3f(K2, K3, kf);                      \
            K0 = n0; K1 = n1; K2 = n2; K3 = n3; }
        {
            float s0 = fmaf(-2.f, accA[0], nv.x + niA); INS(kA0, kA1, kA2, kA3, s0, idb + 0);
            float s1 = fmaf(-2.f, accA[1], nv.y + niA); INS(kA0, kA1, kA2, kA3, s1, idb + 1);
            float s2 = fmaf(-2.f, accA[2], nv.z + niA); INS(kA0, kA1, kA2, kA3, s2, idb + 2);
            float s3 = fmaf(-2.f, accA[3], nv.w + niA); INS(kA0, kA1, kA2, kA3, s3, idb + 3);
        }
        {
            float s0 = fmaf(-2.f, accB[0], nv.x + niB); INS(kB0, kB1, kB2, kB3, s0, idb + 0);
            float s1 = fmaf(-2.f, accB[1], nv.y + niB); INS(kB0, kB1, kB2, kB3, s1, idb + 1);
            float s2 = fmaf(-2.f, accB[2], nv.z + niB); INS(kB0, kB1, kB2, kB3, s2, idb + 2);
            float s3 = fmaf(-2.f, accB[3], nv.w + niB); INS(kB0, kB1, kB2, kB3, s3, idb + 3);
        }
        #undef INS
    }

    // Epilogue: merge 4 lq-stripes -> top-4; re-pack with GLOBAL j (11 bits).
    __syncthreads();
    {
        float* pa = fbuf + (w * 32 + lr) * 16 + lq * 4;
        pa[0] = kA0; pa[1] = kA1; pa[2] = kA2; pa[3] = kA3;
        float* pb = fbuf + (w * 32 + 16 + lr) * 16 + lq * 4;
        pb[0] = kB0; pb[1] = kB1; pb[2] = kB2; pb[3] = kB3;
    }
    __syncthreads();
    if (l < 32) {
        int rloc = w * 32 + l;
        const float* pr = fbuf + rloc * 16;
        float m0 = INF, m1 = INF, m2 = INF, m3 = INF;
        #pragma unroll
        for (int q2 = 0; q2 < 16; ++q2) {
            float kf = pr[q2];
            float n0 = fminf(m0, kf);
            float n1 = __builtin_amdgcn_fmed3f(m0, m1, kf);
            float n2 = __builtin_amdgcn_fmed3f(m1, m2, kf);
            float n3 = __builtin_amdgcn_fmed3f(m2, m3, kf);
            m0 = n0; m1 = n1; m2 = n2; m3 = n3;
        }
        f32x4 kv;
        #define REPACK(mf, slot) { unsigned u = __float_as_uint(mf); unsigned loc = u & 1023u; \
            unsigned jg = (unsigned)jBase + (((loc >> 2) & 63u) << 4) + ((loc >> 8) << 2) + (loc & 3u); \
            kv[slot] = __uint_as_float((u & 0xFFFFF800u) | jg); }
        REPACK(m0, 0); REPACK(m1, 1); REPACK(m2, 2); REPACK(m3, 3);
        #undef REPACK
        int row = bT + i0 + rloc;
        *(f32x4*)(candf + (size_t)row * 32 + h * 4) = kv;
    }
}

// ---------------------------------------------------------------------------
// Fused merge + refine + gather + conv. Block = (b, 32-i tile), 1024 blocks.
// Phase 0: 1 thread/row merges 32 keys -> top-8 (R8-validated screen depth).
// Phase 1: R7-validated 8-cand exact fp32 butterfly refine, (s,j)-lex.
// Phase 2/3: unchanged from R10 (bitwise-identical conv chain).
// ---------------------------------------------------------------------------
__global__ __launch_bounds__(256, 4) void conv_fused_kernel(const float* __restrict__ ws,
                                                            const float* __restrict__ bias,
                                                            float* __restrict__ out) {
    const float*  xT    = ws + XT_OFF;
    const float*  nsq   = ws + NSQ_OFF;
    const float*  Wt    = ws + WT_OFF;
    const float*  candf = ws + CAND_OFF;

    __shared__ float  g_s[192 * 32];
    __shared__ ushort jcand[32 * 8];
    __shared__ int    jsel3[32 * 3];

    int bb  = blockIdx.x >> 6;
    int i0  = (blockIdx.x & 63) * 32;
    int tid = threadIdx.x;
    int w = tid >> 6, l = tid & 63, qw = l >> 4, lr = l & 15;
    int bT = bb * T_;
    const float INF = __builtin_inff();

    // --- Phase 0: per-row merge of 32 packed keys -> global top-8, decode ids
    if (tid < 32) {
        const float* pk = candf + (size_t)(bT + i0 + tid) * 32;
        float m0 = INF, m1 = INF, m2 = INF, m3 = INF;
        float m4 = INF, m5 = INF, m6 = INF, m7 = INF;
        #pragma unroll
        for (int q = 0; q < 32; ++q) {
            float kf = pk[q];
            float n0 = fminf(m0, kf);
            float n1 = __builtin_amdgcn_fmed3f(m0, m1, kf);
            float n2 = __builtin_amdgcn_fmed3f(m1, m2, kf);
            float n3 = __builtin_amdgcn_fmed3f(m2, m3, kf);
            float n4 = __builtin_amdgcn_fmed3f(m3, m4, kf);
            float n5 = __builtin_amdgcn_fmed3f(m4, m5, kf);
            float n6 = __builtin_amdgcn_fmed3f(m5, m6, kf);
            float n7 = __builtin_amdgcn_fmed3f(m6, m7, kf);
            m0 = n0; m1 = n1; m2 = n2; m3 = n3;
            m4 = n4; m5 = n5; m6 = n6; m7 = n7;
        }
        ushort* dst = jcand + tid * 8;
        dst[0] = (ushort)(__float_as_uint(m0) & 2047u);
        dst[1] = (ushort)(__float_as_uint(m1) & 2047u);
        dst[2] = (ushort)(__float_as_uint(m2) & 2047u);
        dst[3] = (ushort)(__float_as_uint(m3) & 2047u);
        dst[4] = (ushort)(__float_as_uint(m4) & 2047u);
        dst[5] = (ushort)(__float_as_uint(m5) & 2047u);
        dst[6] = (ushort)(__float_as_uint(m6) & 2047u);
        dst[7] = (ushort)(__float_as_uint(m7) & 2047u);
    }
    __syncthreads();

    // --- Phase 1: exact fp32 refine over 8 cands (R7-validated butterfly)
    #pragma unroll
    for (int it = 0; it < 2; ++it) {
        int rl  = w * 8 + it * 4 + qw;
        int row = bT + i0 + rl;
        float4 av = *(const float4*)(xT + (size_t)row * 64 + lr * 4);
        int jown = jcand[rl * 8 + (lr & 7)];
        float D0 = INF, D1 = INF, D2 = INF;
        int   I0 = 0x7FFFFFFF, I1 = 0x7FFFFFFF, I2 = 0x7FFFFFFF;
        #pragma unroll
        for (int t = 0; t < 8; ++t) {
            int jt = __shfl(jown, (l & 48) + t, 64);
            float4 bv = *(const float4*)(xT + (size_t)(bT + jt) * 64 + lr * 4);
            float p = fmaf(bv.w, av.w, fmaf(bv.z, av.z, fmaf(bv.y, av.y, bv.x * av.x)));
            p += __shfl_xor(p, 1, 64);
            p += __shfl_xor(p, 2, 64);
            p += __shfl_xor(p, 4, 64);
            p += __shfl_xor(p, 8, 64);
            float s = nsq[bT + jt] - 2.f * p;
            bool lt2 = (s < D2) || (s == D2 && jt < I2);
            bool lt1 = (s < D1) || (s == D1 && jt < I1);
            bool lt0 = (s < D0) || (s == D0 && jt < I0);
            float nD2 = lt1 ? D1 : (lt2 ? s : D2); int nI2 = lt1 ? I1 : (lt2 ? jt : I2);
            float nD1 = lt0 ? D0 : (lt1 ? s : D1); int nI1 = lt0 ? I0 : (lt1 ? jt : I1);
            D2 = nD2; I2 = nI2; D1 = nD1; I1 = nI1;
            D0 = lt0 ? s : D0; I0 = lt0 ? jt : I0;
        }
        if (lr == 0) {
            jsel3[rl * 3 + 0] = I0; jsel3[rl * 3 + 1] = I1; jsel3[rl * 3 + 2] = I2;
        }
    }
    __syncthreads();

    // --- Phase 2: gather 3 neighbor rows per i' -> g_s[m][i']
    if (tid < 96) {
        int k  = tid >> 5;
        int ip = tid & 31;
        int j  = jsel3[ip * 3 + k];
        const float4* src = (const float4*)(xT + (size_t)(bT + j) * 64);
        #pragma unroll
        for (int c4 = 0; c4 < 16; ++c4) {
            float4 v = src[c4];
            int mm = k * 64 + c4 * 4;
            g_s[(mm + 0) * 32 + ip] = v.x;
            g_s[(mm + 1) * 32 + ip] = v.y;
            g_s[(mm + 2) * 32 + ip] = v.z;
            g_s[(mm + 3) * 32 + ip] = v.w;
        }
    }
    __syncthreads();

    // --- Phase 3: conv (bitwise-identical fmaf chain to R6-R10)
    int oq = tid >> 4;        // o = oq*4 .. +3
    int iq = tid & 15;        // i' = iq*2, +1
    float a0x = 0.f, a0y = 0.f, a1x = 0.f, a1y = 0.f;
    float a2x = 0.f, a2y = 0.f, a3x = 0.f, a3y = 0.f;
    #pragma unroll 4
    for (int mm = 0; mm < 192; ++mm) {
        float4 wv = *(const float4*)(Wt + mm * 64 + oq * 4);
        float2 gv = *(const float2*)(g_s + mm * 32 + iq * 2);
        a0x = fmaf(wv.x, gv.x, a0x); a0y = fmaf(wv.x, gv.y, a0y);
        a1x = fmaf(wv.y, gv.x, a1x); a1y = fmaf(wv.y, gv.y, a1y);
        a2x = fmaf(wv.z, gv.x, a2x); a2y = fmaf(wv.z, gv.y, a2y);
        a3x = fmaf(wv.w, gv.x, a3x); a3y = fmaf(wv.w, gv.y, a3y);
    }
    int o0 = oq * 4;
    float b0 = bias[o0], b1 = bias[o0 + 1], b2 = bias[o0 + 2], b3 = bias[o0 + 3];
    float2 r0; r0.x = a0x + b0; r0.y = a0y + b0;
    float2 r1; r1.x = a1x + b1; r1.y = a1y + b1;
    float2 r2; r2.x = a2x + b2; r2.y = a2y + b2;
    float2 r3; r3.x = a3x + b3; r3.y = a3y + b3;
    size_t ob = (size_t)(bb * O_ + o0) * T_ + i0 + iq * 2;
    *(float2*)(out + ob)          = r0;
    *(float2*)(out + ob + T_)     = r1;
    *(float2*)(out + ob + 2 * T_) = r2;
    *(float2*)(out + ob + 3 * T_) = r3;
}

// ---------------------------------------------------------------------------
extern "C" void kernel_launch(void* const* d_in, const int* in_sizes, int n_in,
                              void* d_out, int out_size, void* d_ws, size_t ws_size,
                              hipStream_t stream) {
    const float* x    = (const float*)d_in[0];
    const float* W    = (const float*)d_in[1];
    const float* bias = (const float*)d_in[2];
    float* out = (float*)d_out;
    float* ws  = (float*)d_ws;
    // requires ~28 MB workspace

    prep_kernel<<<B_ * (T_ / 64) + 48, 256, 0, stream>>>(x, W, ws);
    knn_mfma_kernel<<<2048, 256, 0, stream>>>(
        (const ushort*)(ws + XF_OFF), ws + NSQ_OFF, ws + CAND_OFF);
    conv_fused_kernel<<<B_ * 64, 256, 0, stream>>>(ws, bias, out);
}